// Round 1
// baseline (463.613 us; speedup 1.0000x reference)
//
#include <hip/hip_runtime.h>

#define HH 128
#define WW 128
#define NB 16
#define FEAT_OFF 2621440ull   // 16*10*128*128
#define ADJ_OFF  2623488ull   // FEAT_OFF + 16*128

typedef __bf16 bf16x8 __attribute__((ext_vector_type(8)));
typedef float  f32x4  __attribute__((ext_vector_type(4)));

__device__ __forceinline__ unsigned short f2bf(float f) {
  unsigned int u = __float_as_uint(f);
  unsigned int r = ((u >> 16) & 1u) + 0x7fffu;
  return (unsigned short)((u + r) >> 16);
}
__device__ __forceinline__ float bf2f(unsigned short s) {
  return __uint_as_float(((unsigned int)s) << 16);
}
__device__ __forceinline__ void gl_lds16(const void* g, void* l) {
  __builtin_amdgcn_global_load_lds((const __attribute__((address_space(1))) unsigned int*)g,
                                   (__attribute__((address_space(3))) unsigned int*)l, 16, 0, 0);
}

// ---------------- prep: weight repack (bf16) + zero page ----------------
// W1t[dy][dx][co][ci] (co=128, ci=256), W2t[dy][dx][co<16][ci=128] (co>=10 zeroed)
__global__ void prep_kernel(const float* __restrict__ w1, const float* __restrict__ w2,
                            unsigned short* __restrict__ W1t, unsigned short* __restrict__ W2t,
                            unsigned short* __restrict__ zp) {
  int id = blockIdx.x * 256 + threadIdx.x;
  if (id < 2048) zp[id] = 0;
  if (id < 294912) {
    int ci = id & 255, co = (id >> 8) & 127, dxy = id >> 15;
    int dy = dxy / 3, dx = dxy - 3 * dy;
    W1t[id] = f2bf(w1[((co * 256 + ci) * 3 + dy) * 3 + dx]);
  }
  if (id < 18432) {
    int ci = id & 127, co = (id >> 7) & 15, dxy = id >> 11;
    int dy = dxy / 3, dx = dxy - 3 * dy;
    W2t[id] = (co < 10) ? f2bf(w2[((co * 128 + ci) * 3 + dy) * 3 + dx]) : (unsigned short)0;
  }
}

// ---------------- NCHW fp32 -> NHWC bf16 ----------------
__global__ void nhwc_kernel(const float* __restrict__ F, unsigned short* __restrict__ Xn) {
  int t = threadIdx.x, bi = blockIdx.x;
  int x = t & 127;
  int cg = ((bi & 7) << 1) | (t >> 7);        // 0..15 (16 channels each)
  int y = (bi >> 3) & 127;
  int b = bi >> 10;
  const float* src = F + (((size_t)(b * 256 + cg * 16)) * HH + y) * WW + x;
  __align__(16) unsigned short v[16];
#pragma unroll
  for (int i = 0; i < 16; ++i) v[i] = f2bf(src[(size_t)i * (HH * WW)]);
  unsigned short* dst = Xn + ((((size_t)b * HH + y) * WW) + x) * 256 + cg * 16;
  *(uint4*)dst = *(const uint4*)&v[0];
  *(uint4*)(dst + 8) = *(const uint4*)&v[8];
}

// ---------------- conv1: 3x3, cin=256 -> cout=128, bf16 MFMA ----------------
// grid: (b,y) = 2048 blocks, 256 threads. Tile: M=128 (x), N=128 (cout).
__global__ __launch_bounds__(256) void conv1_kernel(const unsigned short* __restrict__ X,   // NHWC bf16 [16][128][128][256]
                                                    const unsigned short* __restrict__ Wt,  // [3][3][128][256] bf16
                                                    const float* __restrict__ bias,
                                                    unsigned short* __restrict__ Hout,      // NHWC bf16 [16][128][128][128]
                                                    const unsigned short* __restrict__ zp) {
  __shared__ __align__(16) unsigned short smem[8704];   // A:[144][32]=4608, B:[128][32]=4096 ; epilogue reuses 8192
  unsigned short* As = smem;
  unsigned short* Bs = smem + 4608;
  const int t = threadIdx.x, l = t & 63, w = t >> 6;
  const int b = blockIdx.x >> 7, y = blockIdx.x & 127;
  const int moff = (w & 1) * 64, noff = (w >> 1) * 64;
  const int ko = l >> 4, r0 = l & 15;

  f32x4 acc[4][4];
#pragma unroll
  for (int i = 0; i < 4; ++i)
#pragma unroll
    for (int j = 0; j < 4; ++j) acc[i][j] = {0.f, 0.f, 0.f, 0.f};

  for (int dy = 0; dy < 3; ++dy) {
    int yy = y + dy - 1;
    if (yy < 0 || yy >= HH) continue;
    const unsigned short* Xrow = X + (((size_t)b * HH + yy) * WW) * 256;
    for (int cb = 0; cb < 8; ++cb) {
      __syncthreads();                       // LDS WAR (A and B)
      // stage A ext tile: rows er=0..129 (x_in = er-1), 9 wave-calls of 16 rows
      for (int j = w; j < 9; j += 4) {
        int er = j * 16 + (l >> 2);
        int xin = er - 1;
        int kq = (l & 3) ^ (er & 3);
        const unsigned short* g = (xin >= 0 && xin < WW && er < 130)
                                    ? (Xrow + (size_t)xin * 256 + cb * 32 + kq * 8)
                                    : (zp + l * 8);
        gl_lds16(g, As + j * 512);
      }
      for (int dx = 0; dx < 3; ++dx) {
        if (dx) __syncthreads();             // B WAR
        const unsigned short* Wg = Wt + (((size_t)(dy * 3 + dx)) * 128) * 256 + cb * 32;
        for (int j = w; j < 8; j += 4) {
          int co = j * 16 + (l >> 2);
          int kq = (l & 3) ^ (co & 3);
          gl_lds16(Wg + (size_t)co * 256 + kq * 8, Bs + j * 512);
        }
        __syncthreads();                     // staging visible (barrier drains vmcnt)
        bf16x8 a[4], bb[4];
#pragma unroll
        for (int mf = 0; mf < 4; ++mf) {
          int row = moff + mf * 16 + r0 + dx;
          a[mf] = *(const bf16x8*)(As + row * 32 + ((ko ^ (row & 3)) << 3));
        }
#pragma unroll
        for (int nf = 0; nf < 4; ++nf) {
          int co = noff + nf * 16 + r0;
          bb[nf] = *(const bf16x8*)(Bs + co * 32 + ((ko ^ (co & 3)) << 3));
        }
#pragma unroll
        for (int mf = 0; mf < 4; ++mf)
#pragma unroll
          for (int nf = 0; nf < 4; ++nf)
            acc[mf][nf] = __builtin_amdgcn_mfma_f32_16x16x32_bf16(a[mf], bb[nf], acc[mf][nf], 0, 0, 0);
      }
    }
  }

  // epilogue: bias + relu -> bf16, LDS transpose -> coalesced NHWC store
  unsigned short* Ebuf = smem;               // [64][128] bf16 = 8192 ushorts
  for (int half = 0; half < 2; ++half) {
    __syncthreads();
    if ((w & 1) == half) {
#pragma unroll
      for (int nf = 0; nf < 4; ++nf) {
        int col = noff + nf * 16 + r0;
        float bv = bias[col];
#pragma unroll
        for (int mf = 0; mf < 4; ++mf) {
#pragma unroll
          for (int j = 0; j < 4; ++j) {
            int rloc = mf * 16 + (l >> 4) * 4 + j;
            float v = acc[mf][nf][j] + bv;
            Ebuf[rloc * 128 + col] = f2bf(fmaxf(v, 0.f));
          }
        }
      }
    }
    __syncthreads();
    size_t base = (((size_t)b * HH + y) * WW + half * 64) * 128;   // ushort units
    for (int p = 0; p < 4; ++p) {
      int idx = p * 256 + t;                 // 16B units, 1024 total
      ((uint4*)(Hout + base))[idx] = ((const uint4*)Ebuf)[idx];
    }
  }
}

// ---------------- conv2: 3x3, cin=128 -> cout=10(pad16), sigmoid ----------------
__global__ __launch_bounds__(256) void conv2_kernel(const unsigned short* __restrict__ Hn,  // NHWC bf16 [16][128][128][128]
                                                    const unsigned short* __restrict__ Wt,  // [3][3][16][128] bf16
                                                    const float* __restrict__ bias,
                                                    float* __restrict__ rmaps,              // [16][10][128][128] fp32
                                                    const unsigned short* __restrict__ zp) {
  __shared__ __align__(16) unsigned short smem[5120];   // A:[144][32]=4608, B:[16][32]=512
  unsigned short* As = smem;
  unsigned short* Bs = smem + 4608;
  const int t = threadIdx.x, l = t & 63, w = t >> 6;
  const int b = blockIdx.x >> 7, y = blockIdx.x & 127;
  const int ko = l >> 4, r0 = l & 15;

  f32x4 acc[2];
  acc[0] = {0.f, 0.f, 0.f, 0.f};
  acc[1] = {0.f, 0.f, 0.f, 0.f};

  for (int dy = 0; dy < 3; ++dy) {
    int yy = y + dy - 1;
    if (yy < 0 || yy >= HH) continue;
    const unsigned short* Xrow = Hn + (((size_t)b * HH + yy) * WW) * 128;
    for (int cb = 0; cb < 4; ++cb) {
      __syncthreads();
      for (int j = w; j < 9; j += 4) {
        int er = j * 16 + (l >> 2);
        int xin = er - 1;
        int kq = (l & 3) ^ (er & 3);
        const unsigned short* g = (xin >= 0 && xin < WW && er < 130)
                                    ? (Xrow + (size_t)xin * 128 + cb * 32 + kq * 8)
                                    : (zp + l * 8);
        gl_lds16(g, As + j * 512);
      }
      for (int dx = 0; dx < 3; ++dx) {
        if (dx) __syncthreads();
        if (w == 0) {
          int co = l >> 2;
          int kq = (l & 3) ^ (co & 3);
          gl_lds16(Wt + (((size_t)(dy * 3 + dx)) * 16 + co) * 128 + cb * 32 + kq * 8, Bs);
        }
        __syncthreads();
        bf16x8 bb = *(const bf16x8*)(Bs + r0 * 32 + ((ko ^ (r0 & 3)) << 3));
#pragma unroll
        for (int mf = 0; mf < 2; ++mf) {
          int row = w * 32 + mf * 16 + r0 + dx;
          bf16x8 a = *(const bf16x8*)(As + row * 32 + ((ko ^ (row & 3)) << 3));
          acc[mf] = __builtin_amdgcn_mfma_f32_16x16x32_bf16(a, bb, acc[mf], 0, 0, 0);
        }
      }
    }
  }

  int co = r0;
  if (co < 10) {
    float bv = bias[co];
#pragma unroll
    for (int mf = 0; mf < 2; ++mf) {
      int x = w * 32 + mf * 16 + (l >> 4) * 4;
      float4 o;
      o.x = 1.f / (1.f + __expf(-(acc[mf][0] + bv)));
      o.y = 1.f / (1.f + __expf(-(acc[mf][1] + bv)));
      o.z = 1.f / (1.f + __expf(-(acc[mf][2] + bv)));
      o.w = 1.f / (1.f + __expf(-(acc[mf][3] + bv)));
      *(float4*)&rmaps[(((size_t)b * 10 + co) * HH + y) * WW + x] = o;
    }
  }
}

// ---------------- pooling: fp32 NCHW -> pooled[b][c*64 + py*8+px] ----------------
__global__ void pool_kernel(const float* __restrict__ F, float* __restrict__ pooled) {
  int t = threadIdx.x, bi = blockIdx.x;
  int b = bi >> 8, c = bi & 255;
  int wi = t >> 2, sub = t & 3;
  int py = wi >> 3, px = wi & 7;
  const float* src = F + (((size_t)(b * 256 + c)) * HH + py * 16 + sub * 4) * WW + px * 16;
  float s = 0.f;
  for (int r = 0; r < 4; ++r) {
    const float* row = src + r * WW;
#pragma unroll
    for (int xx = 0; xx < 16; ++xx) s += row[xx];
  }
  s += __shfl_down(s, 1);
  s += __shfl_down(s, 2);
  if (sub == 0) pooled[(size_t)b * 16384 + c * 64 + wi] = s * (1.f / 256.f);
}

// ---------------- lin1: hidden[o][b] = relu(pooled[b]·w[o] + b1[o]) ----------------
__global__ void lin1_kernel(const float* __restrict__ pooled, const float* __restrict__ w1,
                            const float* __restrict__ b1, float* __restrict__ hidden) {
  int o = blockIdx.x, t = threadIdx.x;
  float acc[16];
#pragma unroll
  for (int b = 0; b < 16; ++b) acc[b] = 0.f;
  const float* wr = w1 + (size_t)o * 16384;
  for (int i = t; i < 16384; i += 256) {
    float wv = wr[i];
#pragma unroll
    for (int b = 0; b < 16; ++b) acc[b] += wv * pooled[(size_t)b * 16384 + i];
  }
  __shared__ float red[16][4];
#pragma unroll
  for (int b = 0; b < 16; ++b) {
    float v = acc[b];
    for (int s = 32; s; s >>= 1) v += __shfl_down(v, s);
    if ((t & 63) == 0) red[b][t >> 6] = v;
  }
  __syncthreads();
  if (t < 16) {
    float v = red[t][0] + red[t][1] + red[t][2] + red[t][3] + b1[o];
    hidden[o * 16 + t] = fmaxf(v, 0.f);
  }
}

// ---------------- head: feat (lin2) + adjacency MLP ----------------
__global__ void head_kernel(const float* __restrict__ hidden,
                            const float* __restrict__ w2, const float* __restrict__ b2,
                            const float* __restrict__ a1w, const float* __restrict__ a1b,
                            const float* __restrict__ a2w, const float* __restrict__ a2b,
                            const float* __restrict__ a3w, const float* __restrict__ a3b,
                            float* __restrict__ out) {
  int b = blockIdx.x, t = threadIdx.x;
  __shared__ float hid[256], fs[128], a1[64], a2[32], pv;
  hid[t] = hidden[t * 16 + b];
  __syncthreads();
  if (t < 128) {
    float s = b2[t];
    for (int k = 0; k < 256; ++k) s += hid[k] * w2[t * 256 + k];
    fs[t] = s;
    out[FEAT_OFF + b * 128 + t] = s;
  }
  __syncthreads();
  if (t < 64) {
    float s = a1b[t];
    for (int k = 0; k < 128; ++k) s += fs[k] * (a1w[t * 256 + k] + a1w[t * 256 + 128 + k]);
    a1[t] = fmaxf(s, 0.f);
  }
  __syncthreads();
  if (t < 32) {
    float s = a2b[t];
    for (int k = 0; k < 64; ++k) s += a1[k] * a2w[t * 64 + k];
    a2[t] = fmaxf(s, 0.f);
  }
  __syncthreads();
  if (t == 0) {
    float s = a3b[0];
    for (int k = 0; k < 32; ++k) s += a2[k] * a3w[k];
    pv = 1.f / (1.f + __expf(-s));
  }
  __syncthreads();
  if (t < 100) out[ADJ_OFF + b * 100 + t] = ((t / 10) == (t % 10)) ? 0.f : pv;
}

extern "C" void kernel_launch(void* const* d_in, const int* in_sizes, int n_in,
                              void* d_out, int out_size, void* d_ws, size_t ws_size,
                              hipStream_t stream) {
  const float* F   = (const float*)d_in[0];
  const float* w1  = (const float*)d_in[1];
  const float* b1  = (const float*)d_in[2];
  const float* w2  = (const float*)d_in[3];
  const float* b2  = (const float*)d_in[4];
  const float* l1w = (const float*)d_in[5];
  const float* l1b = (const float*)d_in[6];
  const float* l2w = (const float*)d_in[7];
  const float* l2b = (const float*)d_in[8];
  const float* a1w = (const float*)d_in[9];
  const float* a1b = (const float*)d_in[10];
  const float* a2w = (const float*)d_in[11];
  const float* a2b = (const float*)d_in[12];
  const float* a3w = (const float*)d_in[13];
  const float* a3b = (const float*)d_in[14];
  float* out = (float*)d_out;
  char* ws = (char*)d_ws;

  const size_t zp_off   = 0;                            // 4096 B
  const size_t w1t_off  = 4096;                         // 589824 B
  const size_t w2t_off  = w1t_off + 589824;             // 36864 B
  const size_t xn_off   = w2t_off + 36864;              // 134217728 B
  const size_t hn_off   = xn_off + 134217728ull;        // 67108864 B
  const size_t pool_off = hn_off + 67108864ull;         // 1048576 B
  const size_t hid_off  = pool_off + 1048576ull;        // 16384 B
  const size_t need     = hid_off + 16384ull;
  if (ws_size < need) return;  // learn ws budget from clean failure

  unsigned short* zp  = (unsigned short*)(ws + zp_off);
  unsigned short* W1t = (unsigned short*)(ws + w1t_off);
  unsigned short* W2t = (unsigned short*)(ws + w2t_off);
  unsigned short* Xn  = (unsigned short*)(ws + xn_off);
  unsigned short* Hn  = (unsigned short*)(ws + hn_off);
  float* pooled = (float*)(ws + pool_off);
  float* hidden = (float*)(ws + hid_off);

  prep_kernel<<<1152, 256, 0, stream>>>(w1, w2, W1t, W2t, zp);
  nhwc_kernel<<<16384, 256, 0, stream>>>(F, Xn);
  pool_kernel<<<4096, 256, 0, stream>>>(F, pooled);
  conv1_kernel<<<2048, 256, 0, stream>>>(Xn, W1t, b1, Hn, zp);
  conv2_kernel<<<2048, 256, 0, stream>>>(Hn, W2t, b2, out, zp);
  lin1_kernel<<<256, 256, 0, stream>>>(pooled, l1w, l1b, hidden);
  head_kernel<<<16, 256, 0, stream>>>(hidden, l2w, l2b, a1w, a1b, a2w, a2b, a3w, a3b, out);
}

// Round 3
// 407.719 us; speedup vs baseline: 1.1371x; 1.1371x over previous
//
#include <hip/hip_runtime.h>

#define HH 128
#define WW 128
#define FEAT_OFF 2621440ull   // 16*10*128*128
#define ADJ_OFF  2623488ull   // FEAT_OFF + 16*128

typedef __bf16 bf16x8 __attribute__((ext_vector_type(8)));
typedef float  f32x4  __attribute__((ext_vector_type(4)));

__device__ __forceinline__ unsigned short f2bf(float f) {
  unsigned int u = __float_as_uint(f);
  unsigned int r = ((u >> 16) & 1u) + 0x7fffu;
  return (unsigned short)((u + r) >> 16);
}
__device__ __forceinline__ void gl_lds16(const void* g, void* l) {
  __builtin_amdgcn_global_load_lds((const __attribute__((address_space(1))) unsigned int*)g,
                                   (__attribute__((address_space(3))) unsigned int*)l, 16, 0, 0);
}
__device__ __forceinline__ int SW(int r) { return (r ^ (r >> 2)) & 3; }

#define FENCE() asm volatile("" ::: "memory")
// K-loop barrier: raw (vmcnt stays counted; ds_reads already consumed by MFMAs)
#define BARRIER() do { FENCE(); __builtin_amdgcn_s_barrier(); FENCE(); } while (0)
// Epilogue barrier: ds_write visibility requires lgkmcnt drain BEFORE s_barrier
#define LBAR() do { asm volatile("s_waitcnt lgkmcnt(0)" ::: "memory"); __builtin_amdgcn_s_barrier(); FENCE(); } while (0)

// ---------------- prep: weight repack (bf16) + zero page ----------------
__global__ void prep_kernel(const float* __restrict__ w1, const float* __restrict__ w2,
                            unsigned short* __restrict__ W1t, unsigned short* __restrict__ W2t,
                            unsigned short* __restrict__ zp) {
  int id = blockIdx.x * 256 + threadIdx.x;
  if (id < 2048) zp[id] = 0;
  if (id < 294912) {
    int ci = id & 255, co = (id >> 8) & 127, dxy = id >> 15;
    int dy = dxy / 3, dx = dxy - 3 * dy;
    W1t[id] = f2bf(w1[((co * 256 + ci) * 3 + dy) * 3 + dx]);
  }
  if (id < 18432) {
    int ci = id & 127, co = (id >> 7) & 15, dxy = id >> 11;
    int dy = dxy / 3, dx = dxy - 3 * dy;
    W2t[id] = (co < 10) ? f2bf(w2[((co * 128 + ci) * 3 + dy) * 3 + dx]) : (unsigned short)0;
  }
}

// ---------------- NCHW fp32 -> NHWC bf16 ----------------
__global__ void nhwc_kernel(const float* __restrict__ F, unsigned short* __restrict__ Xn) {
  int t = threadIdx.x, bi = blockIdx.x;
  int x = t & 127;
  int cg = ((bi & 7) << 1) | (t >> 7);
  int y = (bi >> 3) & 127;
  int b = bi >> 10;
  const float* src = F + (((size_t)(b * 256 + cg * 16)) * HH + y) * WW + x;
  __align__(16) unsigned short v[16];
#pragma unroll
  for (int i = 0; i < 16; ++i) v[i] = f2bf(src[(size_t)i * (HH * WW)]);
  unsigned short* dst = Xn + ((((size_t)b * HH + y) * WW) + x) * 256 + cg * 16;
  *(uint4*)dst = *(const uint4*)&v[0];
  *(uint4*)(dst + 8) = *(const uint4*)&v[8];
}

// ---------------- conv1: M=256 (2 rows) x N=128, counted-vmcnt dbuf ----------------
__global__ __launch_bounds__(512) void conv1_kernel(const unsigned short* __restrict__ X,
                                                    const unsigned short* __restrict__ Wt,
                                                    const float* __restrict__ bias,
                                                    unsigned short* __restrict__ Hout,
                                                    const unsigned short* __restrict__ zp) {
  extern __shared__ __align__(16) unsigned short smem[];   // 2 * 21504 ush = 86016 B
  const int t = threadIdx.x, l = t & 63, w = t >> 6;
  int bid = (blockIdx.x & 7) * 128 + (blockIdx.x >> 3);    // XCD-bijective (1024 = 8*128)
  const int b = bid >> 6, y0 = (bid & 63) * 2;
  const int ko = l >> 4, r0 = l & 15;
  const int wr = w >> 1, wc = w & 1;
  const int ir = wr >> 1, xoff = (wr & 1) * 64;

  f32x4 acc[4][4];
#pragma unroll
  for (int i = 0; i < 4; ++i)
#pragma unroll
    for (int j = 0; j < 4; ++j) acc[i][j] = {0.f, 0.f, 0.f, 0.f};

  auto stage = [&](int p, int bufsel) {
    int dy = p >> 3, cb = p & 7;
    unsigned short* buf = smem + bufsel * 21504;
    for (int j = w; j < 18; j += 8) {                      // A: waves 0,1 -> 3 calls; rest 2
      int air = (j >= 9) ? 1 : 0;
      int jj = j - air * 9;
      int er = jj * 16 + (l >> 2);
      int xin = er - 1;
      int row = y0 - 1 + dy + air;
      const unsigned short* g;
      if (row >= 0 && row < HH && xin >= 0 && xin < WW && er < 130) {
        int kq = (l & 3) ^ SW(er);
        g = X + (((size_t)b * HH + row) * WW + xin) * 256 + cb * 32 + kq * 8;
      } else g = zp + l * 8;
      gl_lds16(g, buf + j * 512);
    }
    for (int j = w; j < 24; j += 8) {                      // B: 3 calls each
      int dxi = j >> 3, jj = j & 7;
      int co = jj * 16 + (l >> 2);
      int kq = (l & 3) ^ SW(co);
      gl_lds16(Wt + (((size_t)(dy * 3 + dxi)) * 128 + co) * 256 + cb * 32 + kq * 8,
               buf + 9216 + j * 512);
    }
  };

  stage(0, 0);
  for (int p = 0; p < 24; ++p) {
    if (p < 23) {
      stage(p + 1, (p + 1) & 1);
      FENCE();
      asm volatile("s_waitcnt vmcnt(5)" ::: "memory");     // own phase-p loads done (counted)
    } else {
      FENCE();
      asm volatile("s_waitcnt vmcnt(0)" ::: "memory");
    }
    BARRIER();                                             // all waves' phase-p staging visible
    const unsigned short* buf = smem + (p & 1) * 21504;
    const unsigned short* Ab = buf + ir * 4608;
    const unsigned short* Bb = buf + 9216;
#pragma unroll
    for (int dx = 0; dx < 3; ++dx) {
      bf16x8 a[4], bb[4];
#pragma unroll
      for (int mf = 0; mf < 4; ++mf) {
        int er = xoff + mf * 16 + r0 + dx;
        a[mf] = *(const bf16x8*)(Ab + er * 32 + ((ko ^ SW(er)) << 3));
      }
#pragma unroll
      for (int nf = 0; nf < 4; ++nf) {
        int co = wc * 64 + nf * 16 + r0;
        bb[nf] = *(const bf16x8*)(Bb + dx * 4096 + co * 32 + ((ko ^ SW(co)) << 3));
      }
#pragma unroll
      for (int mf = 0; mf < 4; ++mf)
#pragma unroll
        for (int nf = 0; nf < 4; ++nf)
          acc[mf][nf] = __builtin_amdgcn_mfma_f32_16x16x32_bf16(a[mf], bb[nf], acc[mf][nf], 0, 0, 0);
    }
    BARRIER();                                             // reads done before buffer reuse
  }

  // epilogue: bias+relu -> bf16, LDS transpose -> coalesced NHWC store (4 chunks of 64 M-rows)
  unsigned short* Ebuf = smem;
  for (int c = 0; c < 4; ++c) {
    if (wr == c) {
#pragma unroll
      for (int nf = 0; nf < 4; ++nf) {
        int col = wc * 64 + nf * 16 + r0;
        float bv = bias[col];
#pragma unroll
        for (int mf = 0; mf < 4; ++mf)
#pragma unroll
          for (int j = 0; j < 4; ++j) {
            int rloc = mf * 16 + (l >> 4) * 4 + j;
            Ebuf[rloc * 128 + col] = f2bf(fmaxf(acc[mf][nf][j] + bv, 0.f));
          }
      }
    }
    LBAR();                                                // drain ds_writes, then barrier
    size_t base = (((size_t)b * HH + (y0 + (c >> 1))) * WW + (c & 1) * 64) * 128;
    ((uint4*)(Hout + base))[t] = ((const uint4*)Ebuf)[t];
    ((uint4*)(Hout + base))[t + 512] = ((const uint4*)Ebuf)[t + 512];
    LBAR();                                                // reads done before next chunk's writes
  }
}

// ---------------- conv2: M=128 x N=16, counted-vmcnt dbuf, phase = cb ----------------
__global__ __launch_bounds__(256) void conv2_kernel(const unsigned short* __restrict__ Hn,
                                                    const unsigned short* __restrict__ Wt,
                                                    const float* __restrict__ bias,
                                                    float* __restrict__ rmaps,
                                                    const unsigned short* __restrict__ zp) {
  extern __shared__ __align__(16) unsigned short smem[];   // 2 * 18432 ush = 73728 B
  const int t = threadIdx.x, l = t & 63, w = t >> 6;
  int bid = (blockIdx.x & 7) * 256 + (blockIdx.x >> 3);    // XCD-bijective (2048 = 8*256)
  const int b = bid >> 7, y = bid & 127;
  const int ko = l >> 4, r0 = l & 15;

  f32x4 acc[2];
  acc[0] = {0.f, 0.f, 0.f, 0.f};
  acc[1] = {0.f, 0.f, 0.f, 0.f};

  auto stage = [&](int cb, int bufsel) {
    unsigned short* buf = smem + bufsel * 18432;
    for (int j = w; j < 27; j += 4) {                      // A rows y-1..y+1
      int rr = (j >= 18) ? 2 : ((j >= 9) ? 1 : 0);
      int jj = j - rr * 9;
      int er = jj * 16 + (l >> 2);
      int xin = er - 1;
      int row = y - 1 + rr;
      const unsigned short* g;
      if (row >= 0 && row < HH && xin >= 0 && xin < WW && er < 130) {
        int kq = (l & 3) ^ SW(er);
        g = Hn + (((size_t)b * HH + row) * WW + xin) * 128 + cb * 32 + kq * 8;
      } else g = zp + l * 8;
      gl_lds16(g, buf + j * 512);
    }
    for (int j = w; j < 9; j += 4) {                       // W: tap j
      int co = l >> 2;
      int kq = (l & 3) ^ SW(co);
      gl_lds16(Wt + ((size_t)j * 16 + co) * 128 + cb * 32 + kq * 8, buf + 13824 + j * 512);
    }
  };

  stage(0, 0);
  for (int p = 0; p < 4; ++p) {
    if (p < 3) {
      stage(p + 1, (p + 1) & 1);
      FENCE();
      asm volatile("s_waitcnt vmcnt(8)" ::: "memory");
    } else {
      FENCE();
      asm volatile("s_waitcnt vmcnt(0)" ::: "memory");
    }
    BARRIER();
    const unsigned short* buf = smem + (p & 1) * 18432;
#pragma unroll
    for (int dy = 0; dy < 3; ++dy)
#pragma unroll
      for (int dx = 0; dx < 3; ++dx) {
        int tap = dy * 3 + dx;
        bf16x8 bb = *(const bf16x8*)(buf + 13824 + tap * 512 + r0 * 32 + ((ko ^ SW(r0)) << 3));
#pragma unroll
        for (int mf = 0; mf < 2; ++mf) {
          int er = w * 32 + mf * 16 + r0 + dx;
          bf16x8 a = *(const bf16x8*)(buf + dy * 4608 + er * 32 + ((ko ^ SW(er)) << 3));
          acc[mf] = __builtin_amdgcn_mfma_f32_16x16x32_bf16(a, bb, acc[mf], 0, 0, 0);
        }
      }
    BARRIER();
  }

  // epilogue: sigmoid -> LDS [co][x] f32 -> coalesced store
  float* Ef = (float*)smem;                                // 16*128 f32 = 8 KB (buf0 region, free)
  float bv = (r0 < 10) ? bias[r0] : 0.f;
#pragma unroll
  for (int mf = 0; mf < 2; ++mf)
#pragma unroll
    for (int j = 0; j < 4; ++j) {
      int x = w * 32 + mf * 16 + (l >> 4) * 4 + j;
      Ef[r0 * 128 + x] = 1.f / (1.f + __expf(-(acc[mf][j] + bv)));
    }
  LBAR();                                                  // drain ds_writes, then barrier
  {
    int co = t >> 5, xi = (t & 31) * 4;
    *(float4*)&rmaps[(((size_t)b * 10 + co) * HH + y) * WW + xi] = *(float4*)&Ef[co * 128 + xi];
    if (t < 64) {
      int idx = t + 256;
      co = idx >> 5; xi = (idx & 31) * 4;
      *(float4*)&rmaps[(((size_t)b * 10 + co) * HH + y) * WW + xi] = *(float4*)&Ef[co * 128 + xi];
    }
  }
}

// ---------------- pooling from bf16 NHWC ----------------
__global__ void pool2_kernel(const unsigned short* __restrict__ Xn, float* __restrict__ pooled) {
  int t = threadIdx.x, bi = blockIdx.x;
  int b = bi >> 6, py = (bi >> 3) & 7, px = bi & 7;
  int p = t & 127, half = t >> 7;
  float s0 = 0.f, s1 = 0.f;
  const unsigned short* base = Xn + (((size_t)b * HH + py * 16 + half * 8) * WW + px * 16) * 256 + p * 2;
  for (int i = 0; i < 8; ++i)
#pragma unroll
    for (int j = 0; j < 16; ++j) {
      unsigned int v = *(const unsigned int*)(base + ((size_t)i * WW + j) * 256);
      s0 += __uint_as_float(v << 16);
      s1 += __uint_as_float(v & 0xffff0000u);
    }
  __shared__ float red[2][256];
  red[half][p * 2] = s0;
  red[half][p * 2 + 1] = s1;
  __syncthreads();
  float v = red[0][t] + red[1][t];
  pooled[(size_t)b * 16384 + t * 64 + py * 8 + px] = v * (1.f / 256.f);
}

// ---------------- lin1 ----------------
__global__ void lin1_kernel(const float* __restrict__ pooled, const float* __restrict__ w1,
                            const float* __restrict__ b1, float* __restrict__ hidden) {
  int o = blockIdx.x, t = threadIdx.x;
  float acc[16];
#pragma unroll
  for (int b = 0; b < 16; ++b) acc[b] = 0.f;
  const float* wr = w1 + (size_t)o * 16384;
  for (int i = t; i < 16384; i += 256) {
    float wv = wr[i];
#pragma unroll
    for (int b = 0; b < 16; ++b) acc[b] += wv * pooled[(size_t)b * 16384 + i];
  }
  __shared__ float red[16][4];
#pragma unroll
  for (int b = 0; b < 16; ++b) {
    float v = acc[b];
    for (int s = 32; s; s >>= 1) v += __shfl_down(v, s);
    if ((t & 63) == 0) red[b][t >> 6] = v;
  }
  __syncthreads();
  if (t < 16) {
    float v = red[t][0] + red[t][1] + red[t][2] + red[t][3] + b1[o];
    hidden[o * 16 + t] = fmaxf(v, 0.f);
  }
}

// ---------------- head ----------------
__global__ void head_kernel(const float* __restrict__ hidden,
                            const float* __restrict__ w2, const float* __restrict__ b2,
                            const float* __restrict__ a1w, const float* __restrict__ a1b,
                            const float* __restrict__ a2w, const float* __restrict__ a2b,
                            const float* __restrict__ a3w, const float* __restrict__ a3b,
                            float* __restrict__ out) {
  int b = blockIdx.x, t = threadIdx.x;
  __shared__ float hid[256], fs[128], a1[64], a2[32], pv;
  hid[t] = hidden[t * 16 + b];
  __syncthreads();
  if (t < 128) {
    float s = b2[t];
    for (int k = 0; k < 256; ++k) s += hid[k] * w2[t * 256 + k];
    fs[t] = s;
    out[FEAT_OFF + b * 128 + t] = s;
  }
  __syncthreads();
  if (t < 64) {
    float s = a1b[t];
    for (int k = 0; k < 128; ++k) s += fs[k] * (a1w[t * 256 + k] + a1w[t * 256 + 128 + k]);
    a1[t] = fmaxf(s, 0.f);
  }
  __syncthreads();
  if (t < 32) {
    float s = a2b[t];
    for (int k = 0; k < 64; ++k) s += a1[k] * a2w[t * 64 + k];
    a2[t] = fmaxf(s, 0.f);
  }
  __syncthreads();
  if (t == 0) {
    float s = a3b[0];
    for (int k = 0; k < 32; ++k) s += a2[k] * a3w[k];
    pv = 1.f / (1.f + __expf(-s));
  }
  __syncthreads();
  if (t < 100) out[ADJ_OFF + b * 100 + t] = ((t / 10) == (t % 10)) ? 0.f : pv;
}

extern "C" void kernel_launch(void* const* d_in, const int* in_sizes, int n_in,
                              void* d_out, int out_size, void* d_ws, size_t ws_size,
                              hipStream_t stream) {
  const float* F   = (const float*)d_in[0];
  const float* w1  = (const float*)d_in[1];
  const float* b1  = (const float*)d_in[2];
  const float* w2  = (const float*)d_in[3];
  const float* b2  = (const float*)d_in[4];
  const float* l1w = (const float*)d_in[5];
  const float* l1b = (const float*)d_in[6];
  const float* l2w = (const float*)d_in[7];
  const float* l2b = (const float*)d_in[8];
  const float* a1w = (const float*)d_in[9];
  const float* a1b = (const float*)d_in[10];
  const float* a2w = (const float*)d_in[11];
  const float* a2b = (const float*)d_in[12];
  const float* a3w = (const float*)d_in[13];
  const float* a3b = (const float*)d_in[14];
  float* out = (float*)d_out;
  char* ws = (char*)d_ws;

  const size_t zp_off   = 0;
  const size_t w1t_off  = 4096;
  const size_t w2t_off  = w1t_off + 589824;
  const size_t xn_off   = w2t_off + 36864;
  const size_t hn_off   = xn_off + 134217728ull;
  const size_t pool_off = hn_off + 67108864ull;
  const size_t hid_off  = pool_off + 1048576ull;
  const size_t need     = hid_off + 16384ull;
  if (ws_size < need) return;

  unsigned short* zp  = (unsigned short*)(ws + zp_off);
  unsigned short* W1t = (unsigned short*)(ws + w1t_off);
  unsigned short* W2t = (unsigned short*)(ws + w2t_off);
  unsigned short* Xn  = (unsigned short*)(ws + xn_off);
  unsigned short* Hn  = (unsigned short*)(ws + hn_off);
  float* pooled = (float*)(ws + pool_off);
  float* hidden = (float*)(ws + hid_off);

  hipFuncSetAttribute((const void*)conv1_kernel, hipFuncAttributeMaxDynamicSharedMemorySize, 86016);
  hipFuncSetAttribute((const void*)conv2_kernel, hipFuncAttributeMaxDynamicSharedMemorySize, 73728);

  prep_kernel<<<1152, 256, 0, stream>>>(w1, w2, W1t, W2t, zp);
  nhwc_kernel<<<16384, 256, 0, stream>>>(F, Xn);
  pool2_kernel<<<1024, 256, 0, stream>>>(Xn, pooled);
  conv1_kernel<<<1024, 512, 86016, stream>>>(Xn, W1t, b1, Hn, zp);
  conv2_kernel<<<2048, 256, 73728, stream>>>(Hn, W2t, b2, out, zp);
  lin1_kernel<<<256, 256, 0, stream>>>(pooled, l1w, l1b, hidden);
  head_kernel<<<16, 256, 0, stream>>>(hidden, l2w, l2b, a1w, a1b, a2w, a2b, a3w, a3b, out);
}

// Round 4
// 379.558 us; speedup vs baseline: 1.2215x; 1.0742x over previous
//
#include <hip/hip_runtime.h>

#define HH 128
#define WW 128
#define FEAT_OFF 2621440ull   // 16*10*128*128
#define ADJ_OFF  2623488ull   // FEAT_OFF + 16*128

typedef __bf16 bf16x8 __attribute__((ext_vector_type(8)));
typedef float  f32x4  __attribute__((ext_vector_type(4)));

__device__ __forceinline__ unsigned short f2bf(float f) {
  unsigned int u = __float_as_uint(f);
  unsigned int r = ((u >> 16) & 1u) + 0x7fffu;
  return (unsigned short)((u + r) >> 16);
}
__device__ __forceinline__ void gl_lds16(const void* g, void* l) {
  __builtin_amdgcn_global_load_lds((const __attribute__((address_space(1))) unsigned int*)g,
                                   (__attribute__((address_space(3))) unsigned int*)l, 16, 0, 0);
}
__device__ __forceinline__ int SW(int r) { return (r ^ (r >> 2)) & 3; }

#define FENCE() asm volatile("" ::: "memory")
#define BARRIER() do { FENCE(); __builtin_amdgcn_s_barrier(); FENCE(); } while (0)
#define LBAR() do { asm volatile("s_waitcnt lgkmcnt(0)" ::: "memory"); __builtin_amdgcn_s_barrier(); FENCE(); } while (0)

// ---------------- prep: weight repack (bf16) + zero page ----------------
__global__ void prep_kernel(const float* __restrict__ w1, const float* __restrict__ w2,
                            unsigned short* __restrict__ W1t, unsigned short* __restrict__ W2t,
                            unsigned short* __restrict__ zp) {
  int id = blockIdx.x * 256 + threadIdx.x;
  if (id < 2048) zp[id] = 0;
  if (id < 294912) {
    int ci = id & 255, co = (id >> 8) & 127, dxy = id >> 15;
    int dy = dxy / 3, dx = dxy - 3 * dy;
    W1t[id] = f2bf(w1[((co * 256 + ci) * 3 + dy) * 3 + dx]);
  }
  if (id < 18432) {
    int ci = id & 127, co = (id >> 7) & 15, dxy = id >> 11;
    int dy = dxy / 3, dx = dxy - 3 * dy;
    W2t[id] = (co < 10) ? f2bf(w2[((co * 128 + ci) * 3 + dy) * 3 + dx]) : (unsigned short)0;
  }
}

// ---------------- NCHW fp32 -> NHWC bf16 via LDS transpose ----------------
// grid: 16b x 128y x 2 chalf = 4096 blocks, 256 threads
__global__ void nhwc_kernel(const float* __restrict__ F, unsigned short* __restrict__ Xn) {
  __shared__ __align__(16) unsigned short tile[16384];   // [x 128][ch 128] ush, slot-swizzled
  int t = threadIdx.x, bi = blockIdx.x;
  int chalf = bi & 1, y = (bi >> 1) & 127, b = bi >> 8;
  int c0 = chalf * 128;
  int cp = t >> 2, xq = t & 3;                            // ch-pair 0..63, x-quarter 0..3
  const float* rowA = F + (((size_t)(b * 256 + c0 + cp * 2)) * HH + y) * WW + xq * 32;
  const float* rowB = rowA + (size_t)HH * WW;
  unsigned int* tw = (unsigned int*)tile;
#pragma unroll
  for (int jj = 0; jj < 8; ++jj) {
    float4 va = *(const float4*)(rowA + jj * 4);
    float4 vb = *(const float4*)(rowB + jj * 4);
    float av[4] = {va.x, va.y, va.z, va.w};
    float bv[4] = {vb.x, vb.y, vb.z, vb.w};
#pragma unroll
    for (int e = 0; e < 4; ++e) {
      int x = xq * 32 + jj * 4 + e;
      unsigned int word = (unsigned int)f2bf(av[e]) | ((unsigned int)f2bf(bv[e]) << 16);
      tw[x * 64 + (((cp >> 2) ^ (x & 15)) << 2) + (cp & 3)] = word;
    }
  }
  __syncthreads();
  int x = t >> 1, h = t & 1;
  unsigned short* dst = Xn + ((((size_t)b * HH + y) * WW) + x) * 256 + c0;
#pragma unroll
  for (int k = 0; k < 8; ++k) {
    int s = h * 8 + k;
    *(uint4*)(dst + s * 8) = *(const uint4*)(tile + x * 128 + ((s ^ (x & 15)) << 3));
  }
}

// ---------------- conv1: block = 4 output rows (M=512) x N=128, wave tile 64x128 ----------------
// grid 512 (16 b x 32 yquads), 512 threads (8 waves: yloc=w>>1, xh=w&1)
// LDS/buffer: A = 4 rows x 9 chunks (36 KiB) + B = 3dx x 8 co-chunks (24 KiB) = 60 KiB; x2 dbuf
__global__ __launch_bounds__(512, 2) void conv1_kernel(const unsigned short* __restrict__ X,
                                                       const unsigned short* __restrict__ Wt,
                                                       const float* __restrict__ bias,
                                                       unsigned short* __restrict__ Hout,
                                                       const unsigned short* __restrict__ zp) {
  extern __shared__ __align__(16) unsigned short smem[];   // 2 * 30720 ush = 122880 B
  const int t = threadIdx.x, l = t & 63, w = t >> 6;
  int bid = (blockIdx.x & 7) * 64 + (blockIdx.x >> 3);     // XCD-bijective (512 = 8*64)
  const int b = bid >> 5, y0 = (bid & 31) * 4;
  const int ko = l >> 4, r0 = l & 15;
  const int yloc = w >> 1, xh = w & 1, xoff = xh * 64;

  f32x4 acc[4][8];
#pragma unroll
  for (int i = 0; i < 4; ++i)
#pragma unroll
    for (int j = 0; j < 8; ++j) acc[i][j] = {0.f, 0.f, 0.f, 0.f};

  auto stage = [&](int p, int bufsel) {
    int dy = p >> 3, cb = p & 7;
    unsigned short* buf = smem + bufsel * 30720;
    for (int c = w; c < 60; c += 8) {                      // waves 0-3: 8 chunks, 4-7: 7
      const unsigned short* g;
      if (c < 36) {                                        // A: air = c/9, jj = c%9
        int air = c / 9, jj = c - air * 9;
        int er = jj * 16 + (l >> 2);
        int xin = er - 1;
        int row = y0 - 1 + dy + air;
        if (row >= 0 && row < HH && xin >= 0 && xin < WW && er < 130) {
          int kq = (l & 3) ^ SW(er);
          g = X + (((size_t)b * HH + row) * WW + xin) * 256 + cb * 32 + kq * 8;
        } else g = zp + l * 8;
      } else {                                             // B: cc = c-36: dxi = cc>>3, jj = cc&7
        int cc = c - 36;
        int dxi = cc >> 3, jj = cc & 7;
        int co = jj * 16 + (l >> 2);
        int kq = (l & 3) ^ SW(co);
        g = Wt + (((size_t)(dy * 3 + dxi)) * 128 + co) * 256 + cb * 32 + kq * 8;
      }
      gl_lds16(g, buf + c * 512);
    }
  };

  stage(0, 0);
  for (int p = 0; p < 24; ++p) {
    if (p < 23) {
      stage(p + 1, (p + 1) & 1);
      FENCE();
      asm volatile("s_waitcnt vmcnt(7)" ::: "memory");     // own phase-p loads done (counted)
    } else {
      FENCE();
      asm volatile("s_waitcnt vmcnt(0)" ::: "memory");
    }
    BARRIER();
    const unsigned short* buf = smem + (p & 1) * 30720;
    const unsigned short* Ab = buf + yloc * 4608;          // own input row (air = yloc)
    const unsigned short* Bb = buf + 18432;
#pragma unroll
    for (int dx = 0; dx < 3; ++dx) {
      bf16x8 a[4], bb[8];
#pragma unroll
      for (int mf = 0; mf < 4; ++mf) {
        int er = xoff + mf * 16 + r0 + dx;
        a[mf] = *(const bf16x8*)(Ab + er * 32 + ((ko ^ SW(er)) << 3));
      }
#pragma unroll
      for (int nf = 0; nf < 8; ++nf) {
        int co = nf * 16 + r0;
        bb[nf] = *(const bf16x8*)(Bb + dx * 4096 + co * 32 + ((ko ^ SW(co)) << 3));
      }
#pragma unroll
      for (int mf = 0; mf < 4; ++mf)
#pragma unroll
        for (int nf = 0; nf < 8; ++nf)
          acc[mf][nf] = __builtin_amdgcn_mfma_f32_16x16x32_bf16(a[mf], bb[nf], acc[mf][nf], 0, 0, 0);
    }
    BARRIER();
  }

  // epilogue: bias+relu -> bf16, LDS [yloc][xl 64][co 128] (64KB), coalesced store; 2 rounds by xh
  unsigned short* E = smem;
  for (int r = 0; r < 2; ++r) {
    if (xh == r) {
#pragma unroll
      for (int nf = 0; nf < 8; ++nf) {
        int co = nf * 16 + r0;
        float bv = bias[co];
#pragma unroll
        for (int mf = 0; mf < 4; ++mf)
#pragma unroll
          for (int j = 0; j < 4; ++j) {
            int xl = mf * 16 + ko * 4 + j;
            E[yloc * 8192 + xl * 128 + co] = f2bf(fmaxf(acc[mf][nf][j] + bv, 0.f));
          }
      }
    }
    LBAR();
#pragma unroll
    for (int k = 0; k < 8; ++k) {
      int idx = k * 512 + t;                               // uint4 index 0..4095
      int yl = idx >> 10, rem = idx & 1023;
      int xl = rem >> 4, oct = rem & 15;
      size_t g = (((size_t)b * HH + y0 + yl) * WW + r * 64 + xl) * 128 + oct * 8;
      *(uint4*)(Hout + g) = ((const uint4*)E)[idx];
    }
    LBAR();
  }
}

// ---------------- conv2: block = 4 rows (M=512) x N=16, counted-vmcnt dbuf, phase = cb ----------------
// grid 512, 256 threads (4 waves; wave = y-row). LDS/buffer: A 6 rows x 9 + W 9 taps = 63 chunks
__global__ __launch_bounds__(256) void conv2_kernel(const unsigned short* __restrict__ Hn,
                                                    const unsigned short* __restrict__ Wt,
                                                    const float* __restrict__ bias,
                                                    float* __restrict__ rmaps,
                                                    const unsigned short* __restrict__ zp) {
  extern __shared__ __align__(16) unsigned short smem[];   // 2 * 32256 ush = 129024 B
  const int t = threadIdx.x, l = t & 63, w = t >> 6;
  int bid = (blockIdx.x & 7) * 64 + (blockIdx.x >> 3);     // XCD-bijective (512 = 8*64)
  const int b = bid >> 5, y0 = (bid & 31) * 4;
  const int ko = l >> 4, r0 = l & 15;
  const int yloc = w;

  f32x4 acc[8];
#pragma unroll
  for (int i = 0; i < 8; ++i) acc[i] = {0.f, 0.f, 0.f, 0.f};

  auto stage = [&](int cb, int bufsel) {
    unsigned short* buf = smem + bufsel * 32256;
    for (int c = w; c < 63; c += 4) {                      // waves 0-2: 16 chunks, wave 3: 15
      const unsigned short* g;
      if (c < 54) {                                        // A: air = c/9 (rows y0-1..y0+4)
        int air = c / 9, jj = c - air * 9;
        int er = jj * 16 + (l >> 2);
        int xin = er - 1;
        int row = y0 - 1 + air;
        if (row >= 0 && row < HH && xin >= 0 && xin < WW && er < 130) {
          int kq = (l & 3) ^ SW(er);
          g = Hn + (((size_t)b * HH + row) * WW + xin) * 128 + cb * 32 + kq * 8;
        } else g = zp + l * 8;
      } else {                                             // W: tap = c-54
        int tap = c - 54;
        int co = l >> 2;
        int kq = (l & 3) ^ SW(co);
        g = Wt + ((size_t)tap * 16 + co) * 128 + cb * 32 + kq * 8;
      }
      gl_lds16(g, buf + c * 512);
    }
  };

  stage(0, 0);
  for (int p = 0; p < 4; ++p) {
    if (p < 3) {
      stage(p + 1, (p + 1) & 1);
      FENCE();
      asm volatile("s_waitcnt vmcnt(15)" ::: "memory");
    } else {
      FENCE();
      asm volatile("s_waitcnt vmcnt(0)" ::: "memory");
    }
    BARRIER();
    const unsigned short* buf = smem + (p & 1) * 32256;
#pragma unroll
    for (int dy = 0; dy < 3; ++dy) {
      const unsigned short* Ab = buf + (yloc + dy) * 4608; // input row = y0-1+(yloc+dy)
#pragma unroll
      for (int dx = 0; dx < 3; ++dx) {
        int tap = dy * 3 + dx;
        bf16x8 bbf = *(const bf16x8*)(buf + (54 + tap) * 512 + r0 * 32 + ((ko ^ SW(r0)) << 3));
#pragma unroll
        for (int mf = 0; mf < 8; ++mf) {
          int er = mf * 16 + r0 + dx;
          bf16x8 a = *(const bf16x8*)(Ab + er * 32 + ((ko ^ SW(er)) << 3));
          acc[mf] = __builtin_amdgcn_mfma_f32_16x16x32_bf16(a, bbf, acc[mf], 0, 0, 0);
        }
      }
    }
    BARRIER();
  }

  // epilogue: sigmoid, direct float4 stores (10.5 MB total; scattered OK)
  int co = r0;
  if (co < 10) {
    float bv = bias[co];
    int y = y0 + yloc;
#pragma unroll
    for (int mf = 0; mf < 8; ++mf) {
      int x = mf * 16 + ko * 4;
      float4 o;
      o.x = 1.f / (1.f + __expf(-(acc[mf][0] + bv)));
      o.y = 1.f / (1.f + __expf(-(acc[mf][1] + bv)));
      o.z = 1.f / (1.f + __expf(-(acc[mf][2] + bv)));
      o.w = 1.f / (1.f + __expf(-(acc[mf][3] + bv)));
      *(float4*)&rmaps[(((size_t)b * 10 + co) * HH + y) * WW + x] = o;
    }
  }
}

// ---------------- pooling from bf16 NHWC ----------------
__global__ void pool2_kernel(const unsigned short* __restrict__ Xn, float* __restrict__ pooled) {
  int t = threadIdx.x, bi = blockIdx.x;
  int b = bi >> 6, py = (bi >> 3) & 7, px = bi & 7;
  int p = t & 127, half = t >> 7;
  float s0 = 0.f, s1 = 0.f;
  const unsigned short* base = Xn + (((size_t)b * HH + py * 16 + half * 8) * WW + px * 16) * 256 + p * 2;
  for (int i = 0; i < 8; ++i)
#pragma unroll
    for (int j = 0; j < 16; ++j) {
      unsigned int v = *(const unsigned int*)(base + ((size_t)i * WW + j) * 256);
      s0 += __uint_as_float(v << 16);
      s1 += __uint_as_float(v & 0xffff0000u);
    }
  __shared__ float red[2][256];
  red[half][p * 2] = s0;
  red[half][p * 2 + 1] = s1;
  __syncthreads();
  float v = red[0][t] + red[1][t];
  pooled[(size_t)b * 16384 + t * 64 + py * 8 + px] = v * (1.f / 256.f);
}

// ---------------- lin1 ----------------
__global__ void lin1_kernel(const float* __restrict__ pooled, const float* __restrict__ w1,
                            const float* __restrict__ b1, float* __restrict__ hidden) {
  int o = blockIdx.x, t = threadIdx.x;
  float acc[16];
#pragma unroll
  for (int b = 0; b < 16; ++b) acc[b] = 0.f;
  const float* wr = w1 + (size_t)o * 16384;
  for (int i = t; i < 16384; i += 256) {
    float wv = wr[i];
#pragma unroll
    for (int b = 0; b < 16; ++b) acc[b] += wv * pooled[(size_t)b * 16384 + i];
  }
  __shared__ float red[16][4];
#pragma unroll
  for (int b = 0; b < 16; ++b) {
    float v = acc[b];
    for (int s = 32; s; s >>= 1) v += __shfl_down(v, s);
    if ((t & 63) == 0) red[b][t >> 6] = v;
  }
  __syncthreads();
  if (t < 16) {
    float v = red[t][0] + red[t][1] + red[t][2] + red[t][3] + b1[o];
    hidden[o * 16 + t] = fmaxf(v, 0.f);
  }
}

// ---------------- head ----------------
__global__ void head_kernel(const float* __restrict__ hidden,
                            const float* __restrict__ w2, const float* __restrict__ b2,
                            const float* __restrict__ a1w, const float* __restrict__ a1b,
                            const float* __restrict__ a2w, const float* __restrict__ a2b,
                            const float* __restrict__ a3w, const float* __restrict__ a3b,
                            float* __restrict__ out) {
  int b = blockIdx.x, t = threadIdx.x;
  __shared__ float hid[256], fs[128], a1[64], a2[32], pv;
  hid[t] = hidden[t * 16 + b];
  __syncthreads();
  if (t < 128) {
    float s = b2[t];
    for (int k = 0; k < 256; ++k) s += hid[k] * w2[t * 256 + k];
    fs[t] = s;
    out[FEAT_OFF + b * 128 + t] = s;
  }
  __syncthreads();
  if (t < 64) {
    float s = a1b[t];
    for (int k = 0; k < 128; ++k) s += fs[k] * (a1w[t * 256 + k] + a1w[t * 256 + 128 + k]);
    a1[t] = fmaxf(s, 0.f);
  }
  __syncthreads();
  if (t < 32) {
    float s = a2b[t];
    for (int k = 0; k < 64; ++k) s += a1[k] * a2w[t * 64 + k];
    a2[t] = fmaxf(s, 0.f);
  }
  __syncthreads();
  if (t == 0) {
    float s = a3b[0];
    for (int k = 0; k < 32; ++k) s += a2[k] * a3w[k];
    pv = 1.f / (1.f + __expf(-s));
  }
  __syncthreads();
  if (t < 100) out[ADJ_OFF + b * 100 + t] = ((t / 10) == (t % 10)) ? 0.f : pv;
}

extern "C" void kernel_launch(void* const* d_in, const int* in_sizes, int n_in,
                              void* d_out, int out_size, void* d_ws, size_t ws_size,
                              hipStream_t stream) {
  const float* F   = (const float*)d_in[0];
  const float* w1  = (const float*)d_in[1];
  const float* b1  = (const float*)d_in[2];
  const float* w2  = (const float*)d_in[3];
  const float* b2  = (const float*)d_in[4];
  const float* l1w = (const float*)d_in[5];
  const float* l1b = (const float*)d_in[6];
  const float* l2w = (const float*)d_in[7];
  const float* l2b = (const float*)d_in[8];
  const float* a1w = (const float*)d_in[9];
  const float* a1b = (const float*)d_in[10];
  const float* a2w = (const float*)d_in[11];
  const float* a2b = (const float*)d_in[12];
  const float* a3w = (const float*)d_in[13];
  const float* a3b = (const float*)d_in[14];
  float* out = (float*)d_out;
  char* ws = (char*)d_ws;

  const size_t zp_off   = 0;
  const size_t w1t_off  = 4096;
  const size_t w2t_off  = w1t_off + 589824;
  const size_t xn_off   = w2t_off + 36864;
  const size_t hn_off   = xn_off + 134217728ull;
  const size_t pool_off = hn_off + 67108864ull;
  const size_t hid_off  = pool_off + 1048576ull;
  const size_t need     = hid_off + 16384ull;
  if (ws_size < need) return;

  unsigned short* zp  = (unsigned short*)(ws + zp_off);
  unsigned short* W1t = (unsigned short*)(ws + w1t_off);
  unsigned short* W2t = (unsigned short*)(ws + w2t_off);
  unsigned short* Xn  = (unsigned short*)(ws + xn_off);
  unsigned short* Hn  = (unsigned short*)(ws + hn_off);
  float* pooled = (float*)(ws + pool_off);
  float* hidden = (float*)(ws + hid_off);

  hipFuncSetAttribute((const void*)conv1_kernel, hipFuncAttributeMaxDynamicSharedMemorySize, 122880);
  hipFuncSetAttribute((const void*)conv2_kernel, hipFuncAttributeMaxDynamicSharedMemorySize, 129024);

  prep_kernel<<<1152, 256, 0, stream>>>(w1, w2, W1t, W2t, zp);
  nhwc_kernel<<<4096, 256, 0, stream>>>(F, Xn);
  pool2_kernel<<<1024, 256, 0, stream>>>(Xn, pooled);
  conv1_kernel<<<512, 512, 122880, stream>>>(Xn, W1t, b1, Hn, zp);
  conv2_kernel<<<512, 256, 129024, stream>>>(Hn, W2t, b2, out, zp);
  lin1_kernel<<<256, 256, 0, stream>>>(pooled, l1w, l1b, hidden);
  head_kernel<<<16, 256, 0, stream>>>(hidden, l2w, l2b, a1w, a1b, a2w, a2b, a3w, a3b, out);
}